// Round 5
// baseline (182.706 us; speedup 1.0000x reference)
//
#include <hip/hip_runtime.h>
#include <cstddef>
#include <cstdint>

// ---------------------------------------------------------------------------
// B=8, N=1024, C=768, H=12, hd=64.  All matmuls mfma_f32_16x16x32_bf16.
// R13: qkv_gemm re-tiled 288feat x 128tok, 4 waves, SINGLE-buffer 53KB LDS
// -> 2 blocks/CU, 512 blocks = exactly 2 balanced rounds.  Robust 2-barrier
// __syncthreads loop (no inline-asm waitcnt): block-level overlap (m114)
// covers the stage drain -- R11/R12's 1-block/CU lockstep schedule was
// 5-6x above the 3.5us MFMA floor and regressed 45->61us on codegen jitter.
// Per-wave work/layout/swizzle/epilogues identical to R10/R11 (144x64 out).
// attn_mfma (R12) / proj_gemm / cvt3 unchanged.
// ---------------------------------------------------------------------------

typedef __attribute__((ext_vector_type(4))) float f32x4;
typedef __attribute__((ext_vector_type(8))) __bf16 bf16x8;
typedef __attribute__((ext_vector_type(4))) unsigned int uint4v;
typedef __attribute__((ext_vector_type(2))) unsigned int uint2v;

#define QK_PRESCALE 0.18033688011112042f   // 64^-0.5 * log2(e); softmax uses exp2

// round-half-up bf16: max error 0.5 ulp
__device__ __forceinline__ unsigned short f2bf(float f) {
  return (unsigned short)((__float_as_uint(f) + 0x8000u) >> 16);
}
// pack two floats -> bf16x2 in one v_perm_b32
__device__ __forceinline__ unsigned int pack2bf(float flo, float fhi) {
  unsigned ulo = __float_as_uint(flo) + 0x8000u;
  unsigned uhi = __float_as_uint(fhi) + 0x8000u;
  return __builtin_amdgcn_perm(uhi, ulo, 0x07060302);
}

// one wave instruction: 64 lanes x 16 B -> LDS[base + lane*16]
__device__ __forceinline__ void gl_lds16(const unsigned short* g, unsigned short* l) {
  __builtin_amdgcn_global_load_lds(
      (const __attribute__((address_space(1))) unsigned int*)g,
      (__attribute__((address_space(3))) unsigned int*)l, 16, 0, 0);
}

// ---------------------------------------------------------------------------
// fp32 -> bf16 conversion for x / qkv_w / proj_w in ONE launch.
// ---------------------------------------------------------------------------
__global__ __launch_bounds__(256)
void cvt3_kernel(const float* __restrict__ s0, unsigned short* __restrict__ d0,
                 const float* __restrict__ s1, unsigned short* __restrict__ d1,
                 const float* __restrict__ s2, unsigned short* __restrict__ d2) {
  int bid = blockIdx.x;
  const float* s; unsigned short* d; int i; int n4;
  if (bid < 6144)      { s = s0; d = d0; i = bid * 256 + threadIdx.x;            n4 = 1572864; }
  else if (bid < 7872) { s = s1; d = d1; i = (bid - 6144) * 256 + threadIdx.x;   n4 = 442368; }
  else                 { s = s2; d = d2; i = (bid - 7872) * 256 + threadIdx.x;   n4 = 147456; }
  if (i < n4) {
    float4 v = ((const float4*)s)[i];
    uint2v o;
    o.x = pack2bf(v.x, v.y);
    o.y = pack2bf(v.z, v.w);
    ((uint2v*)d)[i] = o;
  }
}

// ---------------------------------------------------------------------------
// QKV GEMM: A = wqkv (2304 feature rows), B = x (8192 token rows), K = 768.
// Tile: 288 feat x 128 tok, 4 waves (wr = wid>>1 feat-half, wc = wid&1
// tok-half).  Per-wave output 144x64 (9x4 acc, 72 MFMA/K-tile).
// LDS shorts (single buffer): A [0,18432) = 288x64 | B [18432,26624) = 128x64.
// Per K-tile: stage (A 9 chunks + B 4 chunks per wave, gl_lds16) ->
// __syncthreads -> 26 ds_read_b128 + 72 MFMA -> __syncthreads.
// 512 blocks = 8 XCD x (8 tok-groups x 8 ft); 2 blocks/CU resident -> the
// other block's MFMA covers this block's stage drain.
// ---------------------------------------------------------------------------
__global__ __launch_bounds__(256, 2)
void qkv_gemm(const unsigned short* __restrict__ xb, const unsigned short* __restrict__ wb,
              const float* __restrict__ qb, const float* __restrict__ vb,
              unsigned short* __restrict__ qo, unsigned short* __restrict__ ko,
              unsigned short* __restrict__ vto) {
  __shared__ __align__(16) unsigned short lds[26624];  // 52 KiB
  const int tid = threadIdx.x;
  const int lane = tid & 63, wid = tid >> 6;
  const int widu = __builtin_amdgcn_readfirstlane(wid);
  const int lm = lane & 15, lq = lane >> 4;
  const int xsw = lm & 7;
  const int wr = widu >> 1, wc = widu & 1;      // feat-half (144), tok-half (64)
  const int L = blockIdx.x;
  const int xcd = L & 7, s = L >> 3;            // s: 0..63
  const int tt = xcd * 8 + (s >> 3);            // token tile 0..63 (128 toks)
  const int ft = s & 7;                         // feature tile 0..7 (288 feats)
  const int m0 = tt * 128;                      // token base
  const int n0 = ft * 288;                      // feature base
  const int srow = lane >> 3;                   // 0..7
  const int scolsw = ((lane & 7) ^ srow) * 8;   // pre-swizzled source chunk
  const unsigned short* paS = wb + (size_t)(n0 + widu * 72 + srow) * 768 + scolsw;
  const unsigned short* pbS = xb + (size_t)(m0 + widu * 32 + srow) * 768 + scolsw;
  unsigned short* const ldsA = &lds[(widu * 72) * 64];
  unsigned short* const ldsB = &lds[18432 + (widu * 32) * 64];

  f32x4 acc[9][4] = {};

  for (int t = 0; t < 12; ++t) {
    const size_t c = (size_t)t * 64;
    // stage: A rows [wid*72, wid*72+72) in 9 chunks, B rows [wid*32,+32) in 4
#pragma unroll
    for (int i = 0; i < 9; ++i)
      gl_lds16(paS + (size_t)i * 8 * 768 + c, ldsA + i * 8 * 64);
#pragma unroll
    for (int i = 0; i < 4; ++i)
      gl_lds16(pbS + (size_t)i * 8 * 768 + c, ldsB + i * 8 * 64);
    __syncthreads();

    // fragment reads (26 x ds_read_b128) + 72 MFMA, two clusters
    bf16x8 bff[4][2], af[5][2];
#pragma unroll
    for (int n2 = 0; n2 < 4; ++n2)
#pragma unroll
      for (int kx = 0; kx < 2; ++kx)
        bff[n2][kx] = *(const bf16x8*)&lds[18432 + (wc * 64 + n2 * 16 + lm) * 64 + (((kx * 4 + lq) ^ xsw) * 8)];
#pragma unroll
    for (int m2 = 0; m2 < 5; ++m2)
#pragma unroll
      for (int kx = 0; kx < 2; ++kx)
        af[m2][kx] = *(const bf16x8*)&lds[(wr * 144 + m2 * 16 + lm) * 64 + (((kx * 4 + lq) ^ xsw) * 8)];

    __builtin_amdgcn_s_setprio(1);
#pragma unroll
    for (int kx = 0; kx < 2; ++kx)
#pragma unroll
      for (int m2 = 0; m2 < 5; ++m2)
#pragma unroll
        for (int n2 = 0; n2 < 4; ++n2)
          acc[m2][n2] = __builtin_amdgcn_mfma_f32_16x16x32_bf16(af[m2][kx], bff[n2][kx], acc[m2][n2], 0, 0, 0);
    __builtin_amdgcn_s_setprio(0);

    bf16x8 af2[4][2];
#pragma unroll
    for (int m2 = 0; m2 < 4; ++m2)
#pragma unroll
      for (int kx = 0; kx < 2; ++kx)
        af2[m2][kx] = *(const bf16x8*)&lds[(wr * 144 + (5 + m2) * 16 + lm) * 64 + (((kx * 4 + lq) ^ xsw) * 8)];
    __builtin_amdgcn_s_setprio(1);
#pragma unroll
    for (int kx = 0; kx < 2; ++kx)
#pragma unroll
      for (int m2 = 0; m2 < 4; ++m2)
#pragma unroll
        for (int n2 = 0; n2 < 4; ++n2)
          acc[5 + m2][n2] = __builtin_amdgcn_mfma_f32_16x16x32_bf16(af2[m2][kx], bff[n2][kx], acc[5 + m2][n2], 0, 0, 0);
    __builtin_amdgcn_s_setprio(0);

    __syncthreads();   // all reads done before next stage overwrites
  }

  // ---------------- epilogue ----------------
  const int bq = tt >> 3;               // batch
  const int tokb = (tt & 7) * 128;      // token offset within batch
  // q/k rowblocks: direct packed 8B stores (4 consecutive d per lane)
#pragma unroll
  for (int mi = 0; mi < 9; ++mi) {
    const int fblk = n0 + wr * 144 + mi * 16;   // 16-aligned; q/k/v boundary safe
    if (fblk < 1536) {
      const bool isq = fblk < 768;
      unsigned short* dst0 = isq ? qo : ko;
      const int fd = fblk - (isq ? 0 : 768);
      const int hh = fd >> 6;
      const int dih = (fd & 63) + lq * 4;
      f32x4 bias4 = {0.f, 0.f, 0.f, 0.f};
      if (isq) bias4 = *(const f32x4*)&qb[fblk + lq * 4];
#pragma unroll
      for (int ni = 0; ni < 4; ++ni) {
        const int tok = tokb + wc * 64 + ni * 16 + lm;
        uint2v pk;
        if (isq) {
          pk.x = pack2bf((acc[mi][ni][0] + bias4[0]) * QK_PRESCALE,
                         (acc[mi][ni][1] + bias4[1]) * QK_PRESCALE);
          pk.y = pack2bf((acc[mi][ni][2] + bias4[2]) * QK_PRESCALE,
                         (acc[mi][ni][3] + bias4[3]) * QK_PRESCALE);
        } else {
          pk.x = pack2bf(acc[mi][ni][0], acc[mi][ni][1]);
          pk.y = pack2bf(acc[mi][ni][2], acc[mi][ni][3]);
        }
        *(uint2v*)&dst0[(((size_t)(bq * 12 + hh)) * 1024 + tok) * 64 + dih] = pk;
      }
    }
  }
  // v rowblocks: transpose via LDS scratch (144 x stride 136), 2 passes
  if (n0 + 288 > 1536) {
#pragma unroll
    for (int p = 0; p < 2; ++p) {
      __syncthreads();
      if (wr == p) {
#pragma unroll
        for (int mi = 0; mi < 9; ++mi) {
          const int fblk = n0 + p * 144 + mi * 16;
          if (fblk >= 1536) {
            f32x4 bias4 = *(const f32x4*)&vb[fblk - 1536 + lq * 4];
#pragma unroll
            for (int ni = 0; ni < 4; ++ni) {
              const int tokl = wc * 64 + ni * 16 + lm;
#pragma unroll
              for (int r = 0; r < 4; ++r)
                lds[(mi * 16 + lq * 4 + r) * 136 + tokl] = f2bf(acc[mi][ni][r] + bias4[r]);
            }
          }
        }
      }
      __syncthreads();
      const int fv = 1536 - (n0 + p * 144);
      const int rv0 = fv > 0 ? fv : 0;
      for (int r = rv0 + (tid >> 1); r < 144; r += 128) {
        const int tq = tid & 1;
        const int dgv = n0 + p * 144 + r - 1536;      // 0..767
        const int hh = dgv >> 6, d = dgv & 63;
        unsigned short* dstv = vto + (((size_t)(bq * 12 + hh)) * 64 + d) * 1024 + tokb + tq * 64;
        const unsigned short* srcr = &lds[r * 136 + tq * 64];
#pragma unroll
        for (int j = 0; j < 8; ++j)
          *(uint4v*)&dstv[j * 8] = *(const uint4v*)&srcr[j * 8];
      }
    }
  }
}

// ---------------------------------------------------------------------------
// Flash attention. 768 blocks = 8 XCD x (12 bh x 8 q-tiles).  (R12)
// K/V double-buffered (async 1-deep prefetch, 1 barrier/tile), ps halved
// (PV per 32-key half) stride 40 + XOR(lm&8) conflict-free swizzle, mask
// hoisted.  LDS 46KB -> 3 blocks/CU.
// ---------------------------------------------------------------------------
__global__ __launch_bounds__(256, 3)
void attn_mfma(const unsigned short* __restrict__ q, const unsigned short* __restrict__ k,
               const unsigned short* __restrict__ vt, const int* __restrict__ mask,
               unsigned short* __restrict__ ao) {
  __shared__ unsigned short ks_s[2][64 * 64];  // dbuf K [key][hd], swizzled chunks
  __shared__ unsigned short vs_s[2][64 * 64];  // dbuf V [hd][key], swizzled chunks
  __shared__ unsigned short ps[4][32 * 40];    // per-wave P-half [q][32key], stride 40, XOR(lm&8)
  __shared__ float mkl[1024];                  // all mask bias, hoisted
  const int tid = threadIdx.x;
  const int lane = tid & 63, wid = tid >> 6;
  const int lm = lane & 15, lq = lane >> 4;
  const int xsw = lm & 7;
  const int sxor = (lm & 8) >> 1;              // 4 shorts (8B) if lm>=8
  const int L = blockIdx.x;
  const int xcd = L & 7, s = L >> 3;           // s: 0..95
  const int bh = xcd * 12 + s / 8;
  const int qt = s % 8;
  const int bb = bh / 12, hh = bh % 12;
  const unsigned short* qp = q + (size_t)bh * 65536;
  const unsigned short* kp = k + (size_t)bh * 65536;
  const unsigned short* vp = vt + (size_t)bh * 65536;
  const int* mp = mask + bb * 1024;
  const int q0 = qt * 128 + wid * 32;
  const int srow = lane >> 3;
  const int scolsw = ((lane & 7) ^ srow) * 8;
  const unsigned short* gk = kp + (size_t)(wid * 16 + srow) * 64 + scolsw;
  const unsigned short* gv = vp + (size_t)(wid * 16 + srow) * 1024 + scolsw;

#define STAGE_T(kt_, b_) { \
    gl_lds16(gk + (size_t)(kt_) * 4096, &ks_s[b_][(wid * 16) * 64]); \
    gl_lds16(gk + (size_t)(kt_) * 4096 + (size_t)8 * 64, &ks_s[b_][(wid * 16 + 8) * 64]); \
    gl_lds16(gv + (size_t)(kt_) * 64, &vs_s[b_][(wid * 16) * 64]); \
    gl_lds16(gv + (size_t)(kt_) * 64 + (size_t)8 * 1024, &vs_s[b_][(wid * 16 + 8) * 64]); }

  // hoisted mask -> mkl (int4 load, float4 store)
  {
    int4 mv = ((const int4*)mp)[tid];
    float4 f;
    f.x = mv.x ? -1e30f : 0.0f;
    f.y = mv.y ? -1e30f : 0.0f;
    f.z = mv.z ? -1e30f : 0.0f;
    f.w = mv.w ? -1e30f : 0.0f;
    ((float4*)mkl)[tid] = f;
  }

  bf16x8 qf[2][2];
#pragma unroll
  for (int mi = 0; mi < 2; ++mi)
#pragma unroll
    for (int ks2 = 0; ks2 < 2; ++ks2)
      qf[mi][ks2] = *(const bf16x8*)&qp[(size_t)(q0 + mi * 16 + lm) * 64 + ks2 * 32 + lq * 8];
  bf16x8 ones;
#pragma unroll
  for (int i = 0; i < 8; ++i) ones[i] = (__bf16)1.0f;

  f32x4 o_acc[2][4] = {};
  f32x4 l_acc[2] = {};

  // prologue: stage tile 0; __syncthreads drains vmcnt+lgkm (mkl + stage)
  STAGE_T(0, 0);
  __syncthreads();

  for (int kt = 0; kt < 16; ++kt) {
    const int b = kt & 1;
    if (kt) {
      // tile kt's stage (issued at kt-1) complete; all waves past tile kt-1
      asm volatile("s_waitcnt vmcnt(0)\ns_barrier" ::: "memory");
    }
    // async prefetch of tile kt+1 into the other buffer (covered by compute)
    if (kt < 15) STAGE_T(kt + 1, b ^ 1);

    // S^T = K Q^T : col=q=lm, row=key=lq*4+r (+16nt)
    f32x4 st[4][2] = {};
#pragma unroll
    for (int ks2 = 0; ks2 < 2; ++ks2) {
      bf16x8 kf[4];
#pragma unroll
      for (int nt = 0; nt < 4; ++nt)
        kf[nt] = *(const bf16x8*)&ks_s[b][(nt * 16 + lm) * 64 + (((ks2 * 4 + lq) ^ xsw) * 8)];
      __builtin_amdgcn_s_setprio(1);
#pragma unroll
      for (int nt = 0; nt < 4; ++nt)
#pragma unroll
        for (int mi = 0; mi < 2; ++mi)
          st[nt][mi] = __builtin_amdgcn_mfma_f32_16x16x32_bf16(kf[nt], qf[mi][ks2], st[nt][mi], 0, 0, 0);
      __builtin_amdgcn_s_setprio(0);
    }

    // two 32-key halves: softmax -> ps (swizzled) -> PV
#pragma unroll
    for (int h2 = 0; h2 < 2; ++h2) {
#pragma unroll
      for (int ntl = 0; ntl < 2; ++ntl) {
        const int nt = h2 * 2 + ntl;
        f32x4 mv4 = *(const f32x4*)&mkl[kt * 64 + nt * 16 + lq * 4];
#pragma unroll
        for (int mi = 0; mi < 2; ++mi) {
          uint2v pk;
          pk.x = pack2bf(__builtin_amdgcn_exp2f(st[nt][mi][0] + mv4[0]),
                         __builtin_amdgcn_exp2f(st[nt][mi][1] + mv4[1]));
          pk.y = pack2bf(__builtin_amdgcn_exp2f(st[nt][mi][2] + mv4[2]),
                         __builtin_amdgcn_exp2f(st[nt][mi][3] + mv4[3]));
          *(uint2v*)&ps[wid][(mi * 16 + lm) * 40 + ((ntl * 16 + lq * 4) ^ sxor)] = pk;
        }
      }
      // pf: 2x ds_read_b64 per mi (8B granule matches the XOR swizzle)
      bf16x8 pf[2], vf[4];
#pragma unroll
      for (int mi = 0; mi < 2; ++mi) {
        uint2v h0 = *(const uint2v*)&ps[wid][(mi * 16 + lm) * 40 + ((lq * 8) ^ sxor)];
        uint2v h1 = *(const uint2v*)&ps[wid][(mi * 16 + lm) * 40 + ((lq * 8 + 4) ^ sxor)];
        uint4v u; u.x = h0.x; u.y = h0.y; u.z = h1.x; u.w = h1.y;
        pf[mi] = __builtin_bit_cast(bf16x8, u);
      }
#pragma unroll
      for (int nt = 0; nt < 4; ++nt)
        vf[nt] = *(const bf16x8*)&vs_s[b][(nt * 16 + lm) * 64 + (((h2 * 4 + lq) ^ xsw) * 8)];
      __builtin_amdgcn_s_setprio(1);
#pragma unroll
      for (int mi = 0; mi < 2; ++mi) {
#pragma unroll
        for (int nt = 0; nt < 4; ++nt)
          o_acc[mi][nt] = __builtin_amdgcn_mfma_f32_16x16x32_bf16(pf[mi], vf[nt], o_acc[mi][nt], 0, 0, 0);
        l_acc[mi] = __builtin_amdgcn_mfma_f32_16x16x32_bf16(pf[mi], ones, l_acc[mi], 0, 0, 0);
      }
      __builtin_amdgcn_s_setprio(0);
    }
  }
#undef STAGE_T

  // epilogue: ao[b, tok, h*64+d] = O/l  (bf16)
#pragma unroll
  for (int mi = 0; mi < 2; ++mi) {
#pragma unroll
    for (int r = 0; r < 4; ++r) {
      float inv = 1.0f / l_acc[mi][r];
      int tok = q0 + mi * 16 + lq * 4 + r;
#pragma unroll
      for (int nt = 0; nt < 4; ++nt)
        ao[(size_t)(bb * 1024 + tok) * 768 + hh * 64 + nt * 16 + lm] = f2bf(o_acc[mi][nt][r] * inv);
    }
  }
}

// ---------------------------------------------------------------------------
// Proj GEMM: M=8192, N=768, K=768.  (unchanged)
// ---------------------------------------------------------------------------
__global__ __launch_bounds__(256)
void proj_gemm(const unsigned short* __restrict__ ab, const unsigned short* __restrict__ wb,
               const float* __restrict__ pb, float* __restrict__ out) {
  __shared__ unsigned short as[128 * 64];   // w rows
  __shared__ unsigned short bs[128 * 64];   // ao rows
  const int tid = threadIdx.x;
  const int lane = tid & 63, wid = tid >> 6;
  const int lm = lane & 15, lq = lane >> 4;
  const int xsw = lm & 7;
  const int wm = (wid & 1) * 64, wn = (wid >> 1) * 64;
  const int L = blockIdx.x;
  const int xcd = L & 7, s = L >> 3;           // s: 0..47
  const int m0 = (xcd * 8 + s / 6) * 128;
  const int n0 = (s % 6) * 128;
  const int srow = lane >> 3;
  const int scolsw = ((lane & 7) ^ srow) * 8;
  const unsigned short* ga = wb + (size_t)(n0 + wid * 32 + srow) * 768 + scolsw;
  const unsigned short* gb = ab + (size_t)(m0 + wid * 32 + srow) * 768 + scolsw;
  f32x4 acc[4][4] = {};
  for (int kt = 0; kt < 768; kt += 64) {
#pragma unroll
    for (int i = 0; i < 4; ++i) {
      gl_lds16(ga + kt + (size_t)i * 8 * 768, &as[(wid * 32 + i * 8) * 64]);
      gl_lds16(gb + kt + (size_t)i * 8 * 768, &bs[(wid * 32 + i * 8) * 64]);
    }
    __syncthreads();
#pragma unroll
    for (int ks = 0; ks < 2; ++ks) {
      bf16x8 af[4], bf[4];
#pragma unroll
      for (int i = 0; i < 4; ++i)
        af[i] = *(const bf16x8*)&as[(wm + i * 16 + lm) * 64 + (((ks * 4 + lq) ^ xsw) * 8)];
#pragma unroll
      for (int i = 0; i < 4; ++i)
        bf[i] = *(const bf16x8*)&bs[(wn + i * 16 + lm) * 64 + (((ks * 4 + lq) ^ xsw) * 8)];
#pragma unroll
      for (int mi = 0; mi < 4; ++mi)
#pragma unroll
        for (int ni = 0; ni < 4; ++ni)
          acc[mi][ni] = __builtin_amdgcn_mfma_f32_16x16x32_bf16(af[mi], bf[ni], acc[mi][ni], 0, 0, 0);
    }
    __syncthreads();
  }
  // acc rows = n-dim, cols = m-dim
#pragma unroll
  for (int mi = 0; mi < 4; ++mi) {
    int gn0 = n0 + wm + mi * 16 + lq * 4;
    f32x4 bias4 = *(const f32x4*)&pb[gn0];
#pragma unroll
    for (int ni = 0; ni < 4; ++ni) {
      int gm = m0 + wn + ni * 16 + lm;
      f32x4 o;
      o[0] = acc[mi][ni][0] + bias4[0];
      o[1] = acc[mi][ni][1] + bias4[1];
      o[2] = acc[mi][ni][2] + bias4[2];
      o[3] = acc[mi][ni][3] + bias4[3];
      *(f32x4*)&out[(size_t)gm * 768 + gn0] = o;
    }
  }
}

// ---------------------------------------------------------------------------
// ws layout (bf16 elts): xb 6291456 | wqkv 1769472 | wproj 589824 |
//   q 6291456 | k 6291456 | v^T 6291456 | ao 6291456   (~67.6 MB)
// ---------------------------------------------------------------------------
extern "C" void kernel_launch(void* const* d_in, const int* in_sizes, int n_in,
                              void* d_out, int out_size, void* d_ws, size_t ws_size,
                              hipStream_t stream) {
  const float* x      = (const float*)d_in[0];
  const int*   mask   = (const int*)d_in[1];
  const float* qkv_w  = (const float*)d_in[2];
  const float* q_bias = (const float*)d_in[3];
  const float* v_bias = (const float*)d_in[4];
  const float* proj_w = (const float*)d_in[5];
  const float* proj_b = (const float*)d_in[6];
  float* out = (float*)d_out;
  unsigned short* p = (unsigned short*)d_ws;
  unsigned short* xb     = p;              p += 6291456;
  unsigned short* wqkvb  = p;              p += 1769472;
  unsigned short* wprojb = p;              p += 589824;
  unsigned short* qo     = p;              p += 6291456;
  unsigned short* ko     = p;              p += 6291456;
  unsigned short* vto    = p;              p += 6291456;
  unsigned short* ao     = p;

  cvt3_kernel<<<8448, 256, 0, stream>>>(x, xb, qkv_w, wqkvb, proj_w, wprojb);
  qkv_gemm<<<512, 256, 0, stream>>>(xb, wqkvb, q_bias, v_bias, qo, ko, vto);
  attn_mfma<<<768, 256, 0, stream>>>(qo, ko, vto, mask, ao);
  proj_gemm<<<384, 256, 0, stream>>>(ao, wprojb, proj_b, out);
}

// Round 6
// 182.105 us; speedup vs baseline: 1.0033x; 1.0033x over previous
//
#include <hip/hip_runtime.h>
#include <cstddef>
#include <cstdint>

// ---------------------------------------------------------------------------
// B=8, N=1024, C=768, H=12, hd=64.  All matmuls mfma_f32_16x16x32_bf16.
// R14: attn_mfma: P round-trip through LDS (ps) ELIMINATED -- after packing
// P rows to bf16x2 words, 2x v_permlane16_swap_b32 per (mi,half) rearranges
// (A0,B0,A2,B2)/(A1,B1,A3,B3) so each lane holds 8 consecutive keys; the
// residual lq-permutation {0,2,1,3} is absorbed into the V chunk index.
// Kills 16 DS ops/tile/wave + the write->lgkm->read serial hop, and LDS
// 47->36.9KB gives 4 blocks/CU (launch_bounds 256,4).
// R13 finding kept in mind: ~42us of the measured window is the harness's
// 268MB workspace re-poison fill (fixed cost).
// qkv_gemm (R13) / proj_gemm / cvt3 unchanged.
// ---------------------------------------------------------------------------

typedef __attribute__((ext_vector_type(4))) float f32x4;
typedef __attribute__((ext_vector_type(8))) __bf16 bf16x8;
typedef __attribute__((ext_vector_type(4))) unsigned int uint4v;
typedef __attribute__((ext_vector_type(2))) unsigned int uint2v;

#define QK_PRESCALE 0.18033688011112042f   // 64^-0.5 * log2(e); softmax uses exp2

// round-half-up bf16: max error 0.5 ulp
__device__ __forceinline__ unsigned short f2bf(float f) {
  return (unsigned short)((__float_as_uint(f) + 0x8000u) >> 16);
}
// pack two floats -> bf16x2 in one v_perm_b32
__device__ __forceinline__ unsigned int pack2bf(float flo, float fhi) {
  unsigned ulo = __float_as_uint(flo) + 0x8000u;
  unsigned uhi = __float_as_uint(fhi) + 0x8000u;
  return __builtin_amdgcn_perm(uhi, ulo, 0x07060302);
}

// one wave instruction: 64 lanes x 16 B -> LDS[base + lane*16]
__device__ __forceinline__ void gl_lds16(const unsigned short* g, unsigned short* l) {
  __builtin_amdgcn_global_load_lds(
      (const __attribute__((address_space(1))) unsigned int*)g,
      (__attribute__((address_space(3))) unsigned int*)l, 16, 0, 0);
}

// ---------------------------------------------------------------------------
// fp32 -> bf16 conversion for x / qkv_w / proj_w in ONE launch.
// ---------------------------------------------------------------------------
__global__ __launch_bounds__(256)
void cvt3_kernel(const float* __restrict__ s0, unsigned short* __restrict__ d0,
                 const float* __restrict__ s1, unsigned short* __restrict__ d1,
                 const float* __restrict__ s2, unsigned short* __restrict__ d2) {
  int bid = blockIdx.x;
  const float* s; unsigned short* d; int i; int n4;
  if (bid < 6144)      { s = s0; d = d0; i = bid * 256 + threadIdx.x;            n4 = 1572864; }
  else if (bid < 7872) { s = s1; d = d1; i = (bid - 6144) * 256 + threadIdx.x;   n4 = 442368; }
  else                 { s = s2; d = d2; i = (bid - 7872) * 256 + threadIdx.x;   n4 = 147456; }
  if (i < n4) {
    float4 v = ((const float4*)s)[i];
    uint2v o;
    o.x = pack2bf(v.x, v.y);
    o.y = pack2bf(v.z, v.w);
    ((uint2v*)d)[i] = o;
  }
}

// ---------------------------------------------------------------------------
// QKV GEMM: A = wqkv (2304 feature rows), B = x (8192 token rows), K = 768.
// (R13: 288feat x 128tok, 4 waves, single-buffer 52KB LDS, 2 blocks/CU,
// 512 blocks = 2 balanced rounds, plain __syncthreads loop.)
// ---------------------------------------------------------------------------
__global__ __launch_bounds__(256, 2)
void qkv_gemm(const unsigned short* __restrict__ xb, const unsigned short* __restrict__ wb,
              const float* __restrict__ qb, const float* __restrict__ vb,
              unsigned short* __restrict__ qo, unsigned short* __restrict__ ko,
              unsigned short* __restrict__ vto) {
  __shared__ __align__(16) unsigned short lds[26624];  // 52 KiB
  const int tid = threadIdx.x;
  const int lane = tid & 63, wid = tid >> 6;
  const int widu = __builtin_amdgcn_readfirstlane(wid);
  const int lm = lane & 15, lq = lane >> 4;
  const int xsw = lm & 7;
  const int wr = widu >> 1, wc = widu & 1;      // feat-half (144), tok-half (64)
  const int L = blockIdx.x;
  const int xcd = L & 7, s = L >> 3;            // s: 0..63
  const int tt = xcd * 8 + (s >> 3);            // token tile 0..63 (128 toks)
  const int ft = s & 7;                         // feature tile 0..7 (288 feats)
  const int m0 = tt * 128;                      // token base
  const int n0 = ft * 288;                      // feature base
  const int srow = lane >> 3;                   // 0..7
  const int scolsw = ((lane & 7) ^ srow) * 8;   // pre-swizzled source chunk
  const unsigned short* paS = wb + (size_t)(n0 + widu * 72 + srow) * 768 + scolsw;
  const unsigned short* pbS = xb + (size_t)(m0 + widu * 32 + srow) * 768 + scolsw;
  unsigned short* const ldsA = &lds[(widu * 72) * 64];
  unsigned short* const ldsB = &lds[18432 + (widu * 32) * 64];

  f32x4 acc[9][4] = {};

  for (int t = 0; t < 12; ++t) {
    const size_t c = (size_t)t * 64;
    // stage: A rows [wid*72, wid*72+72) in 9 chunks, B rows [wid*32,+32) in 4
#pragma unroll
    for (int i = 0; i < 9; ++i)
      gl_lds16(paS + (size_t)i * 8 * 768 + c, ldsA + i * 8 * 64);
#pragma unroll
    for (int i = 0; i < 4; ++i)
      gl_lds16(pbS + (size_t)i * 8 * 768 + c, ldsB + i * 8 * 64);
    __syncthreads();

    // fragment reads (26 x ds_read_b128) + 72 MFMA, two clusters
    bf16x8 bff[4][2], af[5][2];
#pragma unroll
    for (int n2 = 0; n2 < 4; ++n2)
#pragma unroll
      for (int kx = 0; kx < 2; ++kx)
        bff[n2][kx] = *(const bf16x8*)&lds[18432 + (wc * 64 + n2 * 16 + lm) * 64 + (((kx * 4 + lq) ^ xsw) * 8)];
#pragma unroll
    for (int m2 = 0; m2 < 5; ++m2)
#pragma unroll
      for (int kx = 0; kx < 2; ++kx)
        af[m2][kx] = *(const bf16x8*)&lds[(wr * 144 + m2 * 16 + lm) * 64 + (((kx * 4 + lq) ^ xsw) * 8)];

    __builtin_amdgcn_s_setprio(1);
#pragma unroll
    for (int kx = 0; kx < 2; ++kx)
#pragma unroll
      for (int m2 = 0; m2 < 5; ++m2)
#pragma unroll
        for (int n2 = 0; n2 < 4; ++n2)
          acc[m2][n2] = __builtin_amdgcn_mfma_f32_16x16x32_bf16(af[m2][kx], bff[n2][kx], acc[m2][n2], 0, 0, 0);
    __builtin_amdgcn_s_setprio(0);

    bf16x8 af2[4][2];
#pragma unroll
    for (int m2 = 0; m2 < 4; ++m2)
#pragma unroll
      for (int kx = 0; kx < 2; ++kx)
        af2[m2][kx] = *(const bf16x8*)&lds[(wr * 144 + (5 + m2) * 16 + lm) * 64 + (((kx * 4 + lq) ^ xsw) * 8)];
    __builtin_amdgcn_s_setprio(1);
#pragma unroll
    for (int kx = 0; kx < 2; ++kx)
#pragma unroll
      for (int m2 = 0; m2 < 4; ++m2)
#pragma unroll
        for (int n2 = 0; n2 < 4; ++n2)
          acc[5 + m2][n2] = __builtin_amdgcn_mfma_f32_16x16x32_bf16(af2[m2][kx], bff[n2][kx], acc[5 + m2][n2], 0, 0, 0);
    __builtin_amdgcn_s_setprio(0);

    __syncthreads();   // all reads done before next stage overwrites
  }

  // ---------------- epilogue ----------------
  const int bq = tt >> 3;               // batch
  const int tokb = (tt & 7) * 128;      // token offset within batch
  // q/k rowblocks: direct packed 8B stores (4 consecutive d per lane)
#pragma unroll
  for (int mi = 0; mi < 9; ++mi) {
    const int fblk = n0 + wr * 144 + mi * 16;   // 16-aligned; q/k/v boundary safe
    if (fblk < 1536) {
      const bool isq = fblk < 768;
      unsigned short* dst0 = isq ? qo : ko;
      const int fd = fblk - (isq ? 0 : 768);
      const int hh = fd >> 6;
      const int dih = (fd & 63) + lq * 4;
      f32x4 bias4 = {0.f, 0.f, 0.f, 0.f};
      if (isq) bias4 = *(const f32x4*)&qb[fblk + lq * 4];
#pragma unroll
      for (int ni = 0; ni < 4; ++ni) {
        const int tok = tokb + wc * 64 + ni * 16 + lm;
        uint2v pk;
        if (isq) {
          pk.x = pack2bf((acc[mi][ni][0] + bias4[0]) * QK_PRESCALE,
                         (acc[mi][ni][1] + bias4[1]) * QK_PRESCALE);
          pk.y = pack2bf((acc[mi][ni][2] + bias4[2]) * QK_PRESCALE,
                         (acc[mi][ni][3] + bias4[3]) * QK_PRESCALE);
        } else {
          pk.x = pack2bf(acc[mi][ni][0], acc[mi][ni][1]);
          pk.y = pack2bf(acc[mi][ni][2], acc[mi][ni][3]);
        }
        *(uint2v*)&dst0[(((size_t)(bq * 12 + hh)) * 1024 + tok) * 64 + dih] = pk;
      }
    }
  }
  // v rowblocks: transpose via LDS scratch (144 x stride 136), 2 passes
  if (n0 + 288 > 1536) {
#pragma unroll
    for (int p = 0; p < 2; ++p) {
      __syncthreads();
      if (wr == p) {
#pragma unroll
        for (int mi = 0; mi < 9; ++mi) {
          const int fblk = n0 + p * 144 + mi * 16;
          if (fblk >= 1536) {
            f32x4 bias4 = *(const f32x4*)&vb[fblk - 1536 + lq * 4];
#pragma unroll
            for (int ni = 0; ni < 4; ++ni) {
              const int tokl = wc * 64 + ni * 16 + lm;
#pragma unroll
              for (int r = 0; r < 4; ++r)
                lds[(mi * 16 + lq * 4 + r) * 136 + tokl] = f2bf(acc[mi][ni][r] + bias4[r]);
            }
          }
        }
      }
      __syncthreads();
      const int fv = 1536 - (n0 + p * 144);
      const int rv0 = fv > 0 ? fv : 0;
      for (int r = rv0 + (tid >> 1); r < 144; r += 128) {
        const int tq = tid & 1;
        const int dgv = n0 + p * 144 + r - 1536;      // 0..767
        const int hh = dgv >> 6, d = dgv & 63;
        unsigned short* dstv = vto + (((size_t)(bq * 12 + hh)) * 64 + d) * 1024 + tokb + tq * 64;
        const unsigned short* srcr = &lds[r * 136 + tq * 64];
#pragma unroll
        for (int j = 0; j < 8; ++j)
          *(uint4v*)&dstv[j * 8] = *(const uint4v*)&srcr[j * 8];
      }
    }
  }
}

// ---------------------------------------------------------------------------
// Flash attention. 768 blocks = 8 XCD x (12 bh x 8 q-tiles).
// R14: K/V dbuf + async 1-deep prefetch (R12), P->PV entirely in registers
// via v_permlane16_swap_b32 (no ps LDS buffer).  After swapped-QK^T, lane
// (lm,lq) holds P[key=nt*16+lq*4+r][q=lm]; packing (r0,r1)(r2,r3) of nt=2h2
// (A) and nt=2h2+1 (B) then swap16(a0,b0), swap16(a1,b1) gives words
// (A0,B0,A2,B2)/(A1,B1,A3,B3): lane lq holds 8 consecutive keys with lq-perm
// {0,2,1,3}, absorbed into the V chunk index.  LDS 36.9KB -> 4 blocks/CU.
// ---------------------------------------------------------------------------
__global__ __launch_bounds__(256, 4)
void attn_mfma(const unsigned short* __restrict__ q, const unsigned short* __restrict__ k,
               const unsigned short* __restrict__ vt, const int* __restrict__ mask,
               unsigned short* __restrict__ ao) {
  __shared__ unsigned short ks_s[2][64 * 64];  // dbuf K [key][hd], swizzled chunks
  __shared__ unsigned short vs_s[2][64 * 64];  // dbuf V [hd][key], swizzled chunks
  __shared__ float mkl[1024];                  // all mask bias, hoisted
  const int tid = threadIdx.x;
  const int lane = tid & 63, wid = tid >> 6;
  const int lm = lane & 15, lq = lane >> 4;
  const int xsw = lm & 7;
  const int plq = ((lq & 1) << 1) | (lq >> 1); // V chunk perm {0,2,1,3}
  const int L = blockIdx.x;
  const int xcd = L & 7, s = L >> 3;           // s: 0..95
  const int bh = xcd * 12 + s / 8;
  const int qt = s % 8;
  const int bb = bh / 12, hh = bh % 12;
  const unsigned short* qp = q + (size_t)bh * 65536;
  const unsigned short* kp = k + (size_t)bh * 65536;
  const unsigned short* vp = vt + (size_t)bh * 65536;
  const int* mp = mask + bb * 1024;
  const int q0 = qt * 128 + wid * 32;
  const int srow = lane >> 3;
  const int scolsw = ((lane & 7) ^ srow) * 8;
  const unsigned short* gk = kp + (size_t)(wid * 16 + srow) * 64 + scolsw;
  const unsigned short* gv = vp + (size_t)(wid * 16 + srow) * 1024 + scolsw;

#define STAGE_T(kt_, b_) { \
    gl_lds16(gk + (size_t)(kt_) * 4096, &ks_s[b_][(wid * 16) * 64]); \
    gl_lds16(gk + (size_t)(kt_) * 4096 + (size_t)8 * 64, &ks_s[b_][(wid * 16 + 8) * 64]); \
    gl_lds16(gv + (size_t)(kt_) * 64, &vs_s[b_][(wid * 16) * 64]); \
    gl_lds16(gv + (size_t)(kt_) * 64 + (size_t)8 * 1024, &vs_s[b_][(wid * 16 + 8) * 64]); }

  // hoisted mask -> mkl (int4 load, float4 store)
  {
    int4 mv = ((const int4*)mp)[tid];
    float4 f;
    f.x = mv.x ? -1e30f : 0.0f;
    f.y = mv.y ? -1e30f : 0.0f;
    f.z = mv.z ? -1e30f : 0.0f;
    f.w = mv.w ? -1e30f : 0.0f;
    ((float4*)mkl)[tid] = f;
  }

  bf16x8 qf[2][2];
#pragma unroll
  for (int mi = 0; mi < 2; ++mi)
#pragma unroll
    for (int ks2 = 0; ks2 < 2; ++ks2)
      qf[mi][ks2] = *(const bf16x8*)&qp[(size_t)(q0 + mi * 16 + lm) * 64 + ks2 * 32 + lq * 8];
  bf16x8 ones;
#pragma unroll
  for (int i = 0; i < 8; ++i) ones[i] = (__bf16)1.0f;

  f32x4 o_acc[2][4] = {};
  f32x4 l_acc[2] = {};

  // prologue: stage tile 0; __syncthreads drains vmcnt+lgkm (mkl + stage)
  STAGE_T(0, 0);
  __syncthreads();

  for (int kt = 0; kt < 16; ++kt) {
    const int b = kt & 1;
    if (kt) {
      // tile kt's stage (issued at kt-1) complete; all waves past tile kt-1
      asm volatile("s_waitcnt vmcnt(0)\ns_barrier" ::: "memory");
    }
    // async prefetch of tile kt+1 into the other buffer (covered by compute)
    if (kt < 15) STAGE_T(kt + 1, b ^ 1);

    // S^T = K Q^T : col=q=lm, row=key=lq*4+r (+16nt)
    f32x4 st[4][2] = {};
#pragma unroll
    for (int ks2 = 0; ks2 < 2; ++ks2) {
      bf16x8 kf[4];
#pragma unroll
      for (int nt = 0; nt < 4; ++nt)
        kf[nt] = *(const bf16x8*)&ks_s[b][(nt * 16 + lm) * 64 + (((ks2 * 4 + lq) ^ xsw) * 8)];
      __builtin_amdgcn_s_setprio(1);
#pragma unroll
      for (int nt = 0; nt < 4; ++nt)
#pragma unroll
        for (int mi = 0; mi < 2; ++mi)
          st[nt][mi] = __builtin_amdgcn_mfma_f32_16x16x32_bf16(kf[nt], qf[mi][ks2], st[nt][mi], 0, 0, 0);
      __builtin_amdgcn_s_setprio(0);
    }

    // two 32-key halves: softmax -> in-register transpose (permlane16) -> PV
#pragma unroll
    for (int h2 = 0; h2 < 2; ++h2) {
      bf16x8 pf[2];
#pragma unroll
      for (int mi = 0; mi < 2; ++mi) {
        const int ntA = h2 * 2, ntB = h2 * 2 + 1;
        f32x4 mvA = *(const f32x4*)&mkl[kt * 64 + ntA * 16 + lq * 4];
        f32x4 mvB = *(const f32x4*)&mkl[kt * 64 + ntB * 16 + lq * 4];
        unsigned a0 = pack2bf(__builtin_amdgcn_exp2f(st[ntA][mi][0] + mvA[0]),
                              __builtin_amdgcn_exp2f(st[ntA][mi][1] + mvA[1]));
        unsigned a1 = pack2bf(__builtin_amdgcn_exp2f(st[ntA][mi][2] + mvA[2]),
                              __builtin_amdgcn_exp2f(st[ntA][mi][3] + mvA[3]));
        unsigned b0 = pack2bf(__builtin_amdgcn_exp2f(st[ntB][mi][0] + mvB[0]),
                              __builtin_amdgcn_exp2f(st[ntB][mi][1] + mvB[1]));
        unsigned b1 = pack2bf(__builtin_amdgcn_exp2f(st[ntB][mi][2] + mvB[2]),
                              __builtin_amdgcn_exp2f(st[ntB][mi][3] + mvB[3]));
        // swap odd 16-rows of a with even 16-rows of b:
        // a' = (A0,B0,A2,B2), b' = (A1,B1,A3,B3)
        asm volatile("v_permlane16_swap_b32 %0, %1" : "+v"(a0), "+v"(b0));
        asm volatile("v_permlane16_swap_b32 %0, %1" : "+v"(a1), "+v"(b1));
        uint4v u; u.x = a0; u.y = a1; u.z = b0; u.w = b1;
        pf[mi] = __builtin_bit_cast(bf16x8, u);
      }
      bf16x8 vf[4];
#pragma unroll
      for (int nt = 0; nt < 4; ++nt)
        vf[nt] = *(const bf16x8*)&vs_s[b][(nt * 16 + lm) * 64 + (((h2 * 4 + plq) ^ xsw) * 8)];
      __builtin_amdgcn_s_setprio(1);
#pragma unroll
      for (int mi = 0; mi < 2; ++mi) {
#pragma unroll
        for (int nt = 0; nt < 4; ++nt)
          o_acc[mi][nt] = __builtin_amdgcn_mfma_f32_16x16x32_bf16(pf[mi], vf[nt], o_acc[mi][nt], 0, 0, 0);
        l_acc[mi] = __builtin_amdgcn_mfma_f32_16x16x32_bf16(pf[mi], ones, l_acc[mi], 0, 0, 0);
      }
      __builtin_amdgcn_s_setprio(0);
    }
  }
#undef STAGE_T

  // epilogue: ao[b, tok, h*64+d] = O/l  (bf16)
#pragma unroll
  for (int mi = 0; mi < 2; ++mi) {
#pragma unroll
    for (int r = 0; r < 4; ++r) {
      float inv = 1.0f / l_acc[mi][r];
      int tok = q0 + mi * 16 + lq * 4 + r;
#pragma unroll
      for (int nt = 0; nt < 4; ++nt)
        ao[(size_t)(bb * 1024 + tok) * 768 + hh * 64 + nt * 16 + lm] = f2bf(o_acc[mi][nt][r] * inv);
    }
  }
}

// ---------------------------------------------------------------------------
// Proj GEMM: M=8192, N=768, K=768.  (unchanged)
// ---------------------------------------------------------------------------
__global__ __launch_bounds__(256)
void proj_gemm(const unsigned short* __restrict__ ab, const unsigned short* __restrict__ wb,
               const float* __restrict__ pb, float* __restrict__ out) {
  __shared__ unsigned short as[128 * 64];   // w rows
  __shared__ unsigned short bs[128 * 64];   // ao rows
  const int tid = threadIdx.x;
  const int lane = tid & 63, wid = tid >> 6;
  const int lm = lane & 15, lq = lane >> 4;
  const int xsw = lm & 7;
  const int wm = (wid & 1) * 64, wn = (wid >> 1) * 64;
  const int L = blockIdx.x;
  const int xcd = L & 7, s = L >> 3;           // s: 0..47
  const int m0 = (xcd * 8 + s / 6) * 128;
  const int n0 = (s % 6) * 128;
  const int srow = lane >> 3;
  const int scolsw = ((lane & 7) ^ srow) * 8;
  const unsigned short* ga = wb + (size_t)(n0 + wid * 32 + srow) * 768 + scolsw;
  const unsigned short* gb = ab + (size_t)(m0 + wid * 32 + srow) * 768 + scolsw;
  f32x4 acc[4][4] = {};
  for (int kt = 0; kt < 768; kt += 64) {
#pragma unroll
    for (int i = 0; i < 4; ++i) {
      gl_lds16(ga + kt + (size_t)i * 8 * 768, &as[(wid * 32 + i * 8) * 64]);
      gl_lds16(gb + kt + (size_t)i * 8 * 768, &bs[(wid * 32 + i * 8) * 64]);
    }
    __syncthreads();
#pragma unroll
    for (int ks = 0; ks < 2; ++ks) {
      bf16x8 af[4], bf[4];
#pragma unroll
      for (int i = 0; i < 4; ++i)
        af[i] = *(const bf16x8*)&as[(wm + i * 16 + lm) * 64 + (((ks * 4 + lq) ^ xsw) * 8)];
#pragma unroll
      for (int i = 0; i < 4; ++i)
        bf[i] = *(const bf16x8*)&bs[(wn + i * 16 + lm) * 64 + (((ks * 4 + lq) ^ xsw) * 8)];
#pragma unroll
      for (int mi = 0; mi < 4; ++mi)
#pragma unroll
        for (int ni = 0; ni < 4; ++ni)
          acc[mi][ni] = __builtin_amdgcn_mfma_f32_16x16x32_bf16(af[mi], bf[ni], acc[mi][ni], 0, 0, 0);
    }
    __syncthreads();
  }
  // acc rows = n-dim, cols = m-dim
#pragma unroll
  for (int mi = 0; mi < 4; ++mi) {
    int gn0 = n0 + wm + mi * 16 + lq * 4;
    f32x4 bias4 = *(const f32x4*)&pb[gn0];
#pragma unroll
    for (int ni = 0; ni < 4; ++ni) {
      int gm = m0 + wn + ni * 16 + lm;
      f32x4 o;
      o[0] = acc[mi][ni][0] + bias4[0];
      o[1] = acc[mi][ni][1] + bias4[1];
      o[2] = acc[mi][ni][2] + bias4[2];
      o[3] = acc[mi][ni][3] + bias4[3];
      *(f32x4*)&out[(size_t)gm * 768 + gn0] = o;
    }
  }
}

// ---------------------------------------------------------------------------
// ws layout (bf16 elts): xb 6291456 | wqkv 1769472 | wproj 589824 |
//   q 6291456 | k 6291456 | v^T 6291456 | ao 6291456   (~67.6 MB)
// ---------------------------------------------------------------------------
extern "C" void kernel_launch(void* const* d_in, const int* in_sizes, int n_in,
                              void* d_out, int out_size, void* d_ws, size_t ws_size,
                              hipStream_t stream) {
  const float* x      = (const float*)d_in[0];
  const int*   mask   = (const int*)d_in[1];
  const float* qkv_w  = (const float*)d_in[2];
  const float* q_bias = (const float*)d_in[3];
  const float* v_bias = (const float*)d_in[4];
  const float* proj_w = (const float*)d_in[5];
  const float* proj_b = (const float*)d_in[6];
  float* out = (float*)d_out;
  unsigned short* p = (unsigned short*)d_ws;
  unsigned short* xb     = p;              p += 6291456;
  unsigned short* wqkvb  = p;              p += 1769472;
  unsigned short* wprojb = p;              p += 589824;
  unsigned short* qo     = p;              p += 6291456;
  unsigned short* ko     = p;              p += 6291456;
  unsigned short* vto    = p;              p += 6291456;
  unsigned short* ao     = p;

  cvt3_kernel<<<8448, 256, 0, stream>>>(x, xb, qkv_w, wqkvb, proj_w, wprojb);
  qkv_gemm<<<512, 256, 0, stream>>>(xb, wqkvb, q_bias, v_bias, qo, ko, vto);
  attn_mfma<<<768, 256, 0, stream>>>(qo, ko, vto, mask, ao);
  proj_gemm<<<384, 256, 0, stream>>>(ao, wprojb, proj_b, out);
}

// Round 7
// 179.699 us; speedup vs baseline: 1.0167x; 1.0134x over previous
//
#include <hip/hip_runtime.h>
#include <cstddef>
#include <cstdint>

// ---------------------------------------------------------------------------
// B=8, N=1024, C=768, H=12, hd=64.  All matmuls mfma_f32_16x16x32_bf16.
// R15: occupancy-geometry round (R14 counters: qkv 2 blocks/CU, occupancy
// 15%, MfmaUtil 26 -- latency-stalled, not BW/compute-bound).
//  * qkv_gemm: 288x128 -> 192x128 tile, grid 768 = 3 blocks/CU exactly
//    (LDS 40KB, launch_bounds(256,3)).  192|768 so each block is purely
//    q/k/v -> uniform epilogue.  Same 2-barrier loop.
//  * proj_gemm: 128x128 -> 96x128 tile, grid 512 = 2 blocks/CU balanced
//    (LDS 28KB).  Same loop body.
// attn_mfma (R14 permlane, 0 conflicts) / cvt3 unchanged.
// Fixed harness cost: ~42us workspace re-poison fill in the window.
// ---------------------------------------------------------------------------

typedef __attribute__((ext_vector_type(4))) float f32x4;
typedef __attribute__((ext_vector_type(8))) __bf16 bf16x8;
typedef __attribute__((ext_vector_type(4))) unsigned int uint4v;
typedef __attribute__((ext_vector_type(2))) unsigned int uint2v;

#define QK_PRESCALE 0.18033688011112042f   // 64^-0.5 * log2(e); softmax uses exp2

// round-half-up bf16: max error 0.5 ulp
__device__ __forceinline__ unsigned short f2bf(float f) {
  return (unsigned short)((__float_as_uint(f) + 0x8000u) >> 16);
}
// pack two floats -> bf16x2 in one v_perm_b32
__device__ __forceinline__ unsigned int pack2bf(float flo, float fhi) {
  unsigned ulo = __float_as_uint(flo) + 0x8000u;
  unsigned uhi = __float_as_uint(fhi) + 0x8000u;
  return __builtin_amdgcn_perm(uhi, ulo, 0x07060302);
}

// one wave instruction: 64 lanes x 16 B -> LDS[base + lane*16]
__device__ __forceinline__ void gl_lds16(const unsigned short* g, unsigned short* l) {
  __builtin_amdgcn_global_load_lds(
      (const __attribute__((address_space(1))) unsigned int*)g,
      (__attribute__((address_space(3))) unsigned int*)l, 16, 0, 0);
}

// ---------------------------------------------------------------------------
// fp32 -> bf16 conversion for x / qkv_w / proj_w in ONE launch.
// ---------------------------------------------------------------------------
__global__ __launch_bounds__(256)
void cvt3_kernel(const float* __restrict__ s0, unsigned short* __restrict__ d0,
                 const float* __restrict__ s1, unsigned short* __restrict__ d1,
                 const float* __restrict__ s2, unsigned short* __restrict__ d2) {
  int bid = blockIdx.x;
  const float* s; unsigned short* d; int i; int n4;
  if (bid < 6144)      { s = s0; d = d0; i = bid * 256 + threadIdx.x;            n4 = 1572864; }
  else if (bid < 7872) { s = s1; d = d1; i = (bid - 6144) * 256 + threadIdx.x;   n4 = 442368; }
  else                 { s = s2; d = d2; i = (bid - 7872) * 256 + threadIdx.x;   n4 = 147456; }
  if (i < n4) {
    float4 v = ((const float4*)s)[i];
    uint2v o;
    o.x = pack2bf(v.x, v.y);
    o.y = pack2bf(v.z, v.w);
    ((uint2v*)d)[i] = o;
  }
}

// ---------------------------------------------------------------------------
// QKV GEMM: A = wqkv (2304 feature rows), B = x (8192 token rows), K = 768.
// Tile: 192 feat x 128 tok, 4 waves (wr = wid>>1 feat-half of 96, wc = wid&1
// tok-half of 64).  Per-wave output 96x64 (6x4 acc, 48 MFMA/K-tile).
// LDS shorts (single buffer): A [0,12288) = 192x64 | B [12288,20480) = 128x64.
// Grid 768 = 8 XCD x (12 ft x 8 tloc) = 3 blocks/CU exactly; the other two
// blocks' MFMA phases cover this block's stage drain (m114 overlap).
// 192 | 768 -> every block is purely q, k, or v.
// ---------------------------------------------------------------------------
__global__ __launch_bounds__(256, 3)
void qkv_gemm(const unsigned short* __restrict__ xb, const unsigned short* __restrict__ wb,
              const float* __restrict__ qb, const float* __restrict__ vb,
              unsigned short* __restrict__ qo, unsigned short* __restrict__ ko,
              unsigned short* __restrict__ vto) {
  __shared__ __align__(16) unsigned short lds[20480];  // 40 KiB
  const int tid = threadIdx.x;
  const int lane = tid & 63, wid = tid >> 6;
  const int widu = __builtin_amdgcn_readfirstlane(wid);
  const int lm = lane & 15, lq = lane >> 4;
  const int xsw = lm & 7;
  const int wr = widu >> 1, wc = widu & 1;      // feat-half (96), tok-half (64)
  const int L = blockIdx.x;
  const int xcd = L & 7, s = L >> 3;            // s: 0..95
  const int ft = s >> 3;                        // feature tile 0..11 (192 feats)
  const int tt = xcd * 8 + (s & 7);             // token tile 0..63 (128 toks)
  const int m0 = tt * 128;                      // token base
  const int n0 = ft * 192;                      // feature base
  const int srow = lane >> 3;                   // 0..7
  const int scolsw = ((lane & 7) ^ srow) * 8;   // pre-swizzled source chunk
  const unsigned short* paS = wb + (size_t)(n0 + widu * 48 + srow) * 768 + scolsw;
  const unsigned short* pbS = xb + (size_t)(m0 + widu * 32 + srow) * 768 + scolsw;
  unsigned short* const ldsA = &lds[(widu * 48) * 64];
  unsigned short* const ldsB = &lds[12288 + (widu * 32) * 64];

  f32x4 acc[6][4] = {};

  for (int t = 0; t < 12; ++t) {
    const size_t c = (size_t)t * 64;
    // stage: A rows [wid*48, wid*48+48) in 6 chunks, B rows [wid*32,+32) in 4
#pragma unroll
    for (int i = 0; i < 6; ++i)
      gl_lds16(paS + (size_t)i * 8 * 768 + c, ldsA + i * 8 * 64);
#pragma unroll
    for (int i = 0; i < 4; ++i)
      gl_lds16(pbS + (size_t)i * 8 * 768 + c, ldsB + i * 8 * 64);
    __syncthreads();

    // fragment reads (20 x ds_read_b128) + 48 MFMA, two clusters
    bf16x8 bff[4][2], af[3][2];
#pragma unroll
    for (int n2 = 0; n2 < 4; ++n2)
#pragma unroll
      for (int kx = 0; kx < 2; ++kx)
        bff[n2][kx] = *(const bf16x8*)&lds[12288 + (wc * 64 + n2 * 16 + lm) * 64 + (((kx * 4 + lq) ^ xsw) * 8)];
#pragma unroll
    for (int m2 = 0; m2 < 3; ++m2)
#pragma unroll
      for (int kx = 0; kx < 2; ++kx)
        af[m2][kx] = *(const bf16x8*)&lds[(wr * 96 + m2 * 16 + lm) * 64 + (((kx * 4 + lq) ^ xsw) * 8)];

    __builtin_amdgcn_s_setprio(1);
#pragma unroll
    for (int kx = 0; kx < 2; ++kx)
#pragma unroll
      for (int m2 = 0; m2 < 3; ++m2)
#pragma unroll
        for (int n2 = 0; n2 < 4; ++n2)
          acc[m2][n2] = __builtin_amdgcn_mfma_f32_16x16x32_bf16(af[m2][kx], bff[n2][kx], acc[m2][n2], 0, 0, 0);
    __builtin_amdgcn_s_setprio(0);

    bf16x8 af2[3][2];
#pragma unroll
    for (int m2 = 0; m2 < 3; ++m2)
#pragma unroll
      for (int kx = 0; kx < 2; ++kx)
        af2[m2][kx] = *(const bf16x8*)&lds[(wr * 96 + (3 + m2) * 16 + lm) * 64 + (((kx * 4 + lq) ^ xsw) * 8)];
    __builtin_amdgcn_s_setprio(1);
#pragma unroll
    for (int kx = 0; kx < 2; ++kx)
#pragma unroll
      for (int m2 = 0; m2 < 3; ++m2)
#pragma unroll
        for (int n2 = 0; n2 < 4; ++n2)
          acc[3 + m2][n2] = __builtin_amdgcn_mfma_f32_16x16x32_bf16(af2[m2][kx], bff[n2][kx], acc[3 + m2][n2], 0, 0, 0);
    __builtin_amdgcn_s_setprio(0);

    __syncthreads();   // all reads done before next stage overwrites
  }

  // ---------------- epilogue ----------------
  const int bq = tt >> 3;               // batch
  const int tokb = (tt & 7) * 128;      // token offset within batch
  if (n0 < 1536) {
    // whole block is q or k: direct packed 8B stores (4 consecutive d/lane)
    const bool isq = n0 < 768;
    unsigned short* dst0 = isq ? qo : ko;
#pragma unroll
    for (int mi = 0; mi < 6; ++mi) {
      const int fblk = n0 + wr * 96 + mi * 16;
      const int fd = fblk - (isq ? 0 : 768);
      const int hh = fd >> 6;
      const int dih = (fd & 63) + lq * 4;
      f32x4 bias4 = {0.f, 0.f, 0.f, 0.f};
      if (isq) bias4 = *(const f32x4*)&qb[fblk + lq * 4];
#pragma unroll
      for (int ni = 0; ni < 4; ++ni) {
        const int tok = tokb + wc * 64 + ni * 16 + lm;
        uint2v pk;
        if (isq) {
          pk.x = pack2bf((acc[mi][ni][0] + bias4[0]) * QK_PRESCALE,
                         (acc[mi][ni][1] + bias4[1]) * QK_PRESCALE);
          pk.y = pack2bf((acc[mi][ni][2] + bias4[2]) * QK_PRESCALE,
                         (acc[mi][ni][3] + bias4[3]) * QK_PRESCALE);
        } else {
          pk.x = pack2bf(acc[mi][ni][0], acc[mi][ni][1]);
          pk.y = pack2bf(acc[mi][ni][2], acc[mi][ni][3]);
        }
        *(uint2v*)&dst0[(((size_t)(bq * 12 + hh)) * 1024 + tok) * 64 + dih] = pk;
      }
    }
  } else {
    // whole block is v: transpose via LDS scratch (96 x stride 136), 2 passes
    const int vb0 = n0 - 1536;
#pragma unroll
    for (int p = 0; p < 2; ++p) {
      __syncthreads();
      if (wr == p) {
#pragma unroll
        for (int mi = 0; mi < 6; ++mi) {
          f32x4 bias4 = *(const f32x4*)&vb[vb0 + p * 96 + mi * 16 + lq * 4];
#pragma unroll
          for (int ni = 0; ni < 4; ++ni) {
            const int tokl = wc * 64 + ni * 16 + lm;
#pragma unroll
            for (int r = 0; r < 4; ++r)
              lds[(mi * 16 + lq * 4 + r) * 136 + tokl] = f2bf(acc[mi][ni][r] + bias4[r]);
          }
        }
      }
      __syncthreads();
      for (int r = tid >> 1; r < 96; r += 128) {
        const int tq = tid & 1;
        const int dgv = vb0 + p * 96 + r;             // 0..767
        const int hh = dgv >> 6, d = dgv & 63;
        unsigned short* dstv = vto + (((size_t)(bq * 12 + hh)) * 64 + d) * 1024 + tokb + tq * 64;
        const unsigned short* srcr = &lds[r * 136 + tq * 64];
#pragma unroll
        for (int j = 0; j < 8; ++j)
          *(uint4v*)&dstv[j * 8] = *(const uint4v*)&srcr[j * 8];
      }
    }
  }
}

// ---------------------------------------------------------------------------
// Flash attention. 768 blocks = 8 XCD x (12 bh x 8 q-tiles).  (R14)
// K/V dbuf + async 1-deep prefetch; P->PV in registers via
// v_permlane16_swap_b32; LDS 36.9KB -> 4 blocks/CU.
// ---------------------------------------------------------------------------
__global__ __launch_bounds__(256, 4)
void attn_mfma(const unsigned short* __restrict__ q, const unsigned short* __restrict__ k,
               const unsigned short* __restrict__ vt, const int* __restrict__ mask,
               unsigned short* __restrict__ ao) {
  __shared__ unsigned short ks_s[2][64 * 64];  // dbuf K [key][hd], swizzled chunks
  __shared__ unsigned short vs_s[2][64 * 64];  // dbuf V [hd][key], swizzled chunks
  __shared__ float mkl[1024];                  // all mask bias, hoisted
  const int tid = threadIdx.x;
  const int lane = tid & 63, wid = tid >> 6;
  const int lm = lane & 15, lq = lane >> 4;
  const int xsw = lm & 7;
  const int plq = ((lq & 1) << 1) | (lq >> 1); // V chunk perm {0,2,1,3}
  const int L = blockIdx.x;
  const int xcd = L & 7, s = L >> 3;           // s: 0..95
  const int bh = xcd * 12 + s / 8;
  const int qt = s % 8;
  const int bb = bh / 12, hh = bh % 12;
  const unsigned short* qp = q + (size_t)bh * 65536;
  const unsigned short* kp = k + (size_t)bh * 65536;
  const unsigned short* vp = vt + (size_t)bh * 65536;
  const int* mp = mask + bb * 1024;
  const int q0 = qt * 128 + wid * 32;
  const int srow = lane >> 3;
  const int scolsw = ((lane & 7) ^ srow) * 8;
  const unsigned short* gk = kp + (size_t)(wid * 16 + srow) * 64 + scolsw;
  const unsigned short* gv = vp + (size_t)(wid * 16 + srow) * 1024 + scolsw;

#define STAGE_T(kt_, b_) { \
    gl_lds16(gk + (size_t)(kt_) * 4096, &ks_s[b_][(wid * 16) * 64]); \
    gl_lds16(gk + (size_t)(kt_) * 4096 + (size_t)8 * 64, &ks_s[b_][(wid * 16 + 8) * 64]); \
    gl_lds16(gv + (size_t)(kt_) * 64, &vs_s[b_][(wid * 16) * 64]); \
    gl_lds16(gv + (size_t)(kt_) * 64 + (size_t)8 * 1024, &vs_s[b_][(wid * 16 + 8) * 64]); }

  // hoisted mask -> mkl (int4 load, float4 store)
  {
    int4 mv = ((const int4*)mp)[tid];
    float4 f;
    f.x = mv.x ? -1e30f : 0.0f;
    f.y = mv.y ? -1e30f : 0.0f;
    f.z = mv.z ? -1e30f : 0.0f;
    f.w = mv.w ? -1e30f : 0.0f;
    ((float4*)mkl)[tid] = f;
  }

  bf16x8 qf[2][2];
#pragma unroll
  for (int mi = 0; mi < 2; ++mi)
#pragma unroll
    for (int ks2 = 0; ks2 < 2; ++ks2)
      qf[mi][ks2] = *(const bf16x8*)&qp[(size_t)(q0 + mi * 16 + lm) * 64 + ks2 * 32 + lq * 8];
  bf16x8 ones;
#pragma unroll
  for (int i = 0; i < 8; ++i) ones[i] = (__bf16)1.0f;

  f32x4 o_acc[2][4] = {};
  f32x4 l_acc[2] = {};

  // prologue: stage tile 0; __syncthreads drains vmcnt+lgkm (mkl + stage)
  STAGE_T(0, 0);
  __syncthreads();

  for (int kt = 0; kt < 16; ++kt) {
    const int b = kt & 1;
    if (kt) {
      // tile kt's stage (issued at kt-1) complete; all waves past tile kt-1
      asm volatile("s_waitcnt vmcnt(0)\ns_barrier" ::: "memory");
    }
    // async prefetch of tile kt+1 into the other buffer (covered by compute)
    if (kt < 15) STAGE_T(kt + 1, b ^ 1);

    // S^T = K Q^T : col=q=lm, row=key=lq*4+r (+16nt)
    f32x4 st[4][2] = {};
#pragma unroll
    for (int ks2 = 0; ks2 < 2; ++ks2) {
      bf16x8 kf[4];
#pragma unroll
      for (int nt = 0; nt < 4; ++nt)
        kf[nt] = *(const bf16x8*)&ks_s[b][(nt * 16 + lm) * 64 + (((ks2 * 4 + lq) ^ xsw) * 8)];
      __builtin_amdgcn_s_setprio(1);
#pragma unroll
      for (int nt = 0; nt < 4; ++nt)
#pragma unroll
        for (int mi = 0; mi < 2; ++mi)
          st[nt][mi] = __builtin_amdgcn_mfma_f32_16x16x32_bf16(kf[nt], qf[mi][ks2], st[nt][mi], 0, 0, 0);
      __builtin_amdgcn_s_setprio(0);
    }

    // two 32-key halves: softmax -> in-register transpose (permlane16) -> PV
#pragma unroll
    for (int h2 = 0; h2 < 2; ++h2) {
      bf16x8 pf[2];
#pragma unroll
      for (int mi = 0; mi < 2; ++mi) {
        const int ntA = h2 * 2, ntB = h2 * 2 + 1;
        f32x4 mvA = *(const f32x4*)&mkl[kt * 64 + ntA * 16 + lq * 4];
        f32x4 mvB = *(const f32x4*)&mkl[kt * 64 + ntB * 16 + lq * 4];
        unsigned a0 = pack2bf(__builtin_amdgcn_exp2f(st[ntA][mi][0] + mvA[0]),
                              __builtin_amdgcn_exp2f(st[ntA][mi][1] + mvA[1]));
        unsigned a1 = pack2bf(__builtin_amdgcn_exp2f(st[ntA][mi][2] + mvA[2]),
                              __builtin_amdgcn_exp2f(st[ntA][mi][3] + mvA[3]));
        unsigned b0 = pack2bf(__builtin_amdgcn_exp2f(st[ntB][mi][0] + mvB[0]),
                              __builtin_amdgcn_exp2f(st[ntB][mi][1] + mvB[1]));
        unsigned b1 = pack2bf(__builtin_amdgcn_exp2f(st[ntB][mi][2] + mvB[2]),
                              __builtin_amdgcn_exp2f(st[ntB][mi][3] + mvB[3]));
        // a' = (A0,B0,A2,B2), b' = (A1,B1,A3,B3)
        asm volatile("v_permlane16_swap_b32 %0, %1" : "+v"(a0), "+v"(b0));
        asm volatile("v_permlane16_swap_b32 %0, %1" : "+v"(a1), "+v"(b1));
        uint4v u; u.x = a0; u.y = a1; u.z = b0; u.w = b1;
        pf[mi] = __builtin_bit_cast(bf16x8, u);
      }
      bf16x8 vf[4];
#pragma unroll
      for (int nt = 0; nt < 4; ++nt)
        vf[nt] = *(const bf16x8*)&vs_s[b][(nt * 16 + lm) * 64 + (((h2 * 4 + plq) ^ xsw) * 8)];
      __builtin_amdgcn_s_setprio(1);
#pragma unroll
      for (int mi = 0; mi < 2; ++mi) {
#pragma unroll
        for (int nt = 0; nt < 4; ++nt)
          o_acc[mi][nt] = __builtin_amdgcn_mfma_f32_16x16x32_bf16(pf[mi], vf[nt], o_acc[mi][nt], 0, 0, 0);
        l_acc[mi] = __builtin_amdgcn_mfma_f32_16x16x32_bf16(pf[mi], ones, l_acc[mi], 0, 0, 0);
      }
      __builtin_amdgcn_s_setprio(0);
    }
  }
#undef STAGE_T

  // epilogue: ao[b, tok, h*64+d] = O/l  (bf16)
#pragma unroll
  for (int mi = 0; mi < 2; ++mi) {
#pragma unroll
    for (int r = 0; r < 4; ++r) {
      float inv = 1.0f / l_acc[mi][r];
      int tok = q0 + mi * 16 + lq * 4 + r;
#pragma unroll
      for (int nt = 0; nt < 4; ++nt)
        ao[(size_t)(bb * 1024 + tok) * 768 + hh * 64 + nt * 16 + lm] = f2bf(o_acc[mi][nt][r] * inv);
    }
  }
}

// ---------------------------------------------------------------------------
// Proj GEMM: M=8192, N=768, K=768.  R15: 96feat x 128tok tile, 4 waves,
// grid 512 = 8 XCD x (8 n-tiles x 8 mloc) = 2 blocks/CU balanced.
// LDS 28KB single buffer; same 2-barrier loop as qkv.
// ---------------------------------------------------------------------------
__global__ __launch_bounds__(256, 2)
void proj_gemm(const unsigned short* __restrict__ ab, const unsigned short* __restrict__ wb,
               const float* __restrict__ pb, float* __restrict__ out) {
  __shared__ __align__(16) unsigned short lds[14336];  // A 96x64 | B 128x64
  const int tid = threadIdx.x;
  const int lane = tid & 63, wid = tid >> 6;
  const int widu = __builtin_amdgcn_readfirstlane(wid);
  const int lm = lane & 15, lq = lane >> 4;
  const int xsw = lm & 7;
  const int wr = widu >> 1, wc = widu & 1;      // feat-half (48), tok-half (64)
  const int L = blockIdx.x;
  const int xcd = L & 7, s = L >> 3;            // s: 0..63
  const int n0 = (s >> 3) * 96;                 // feature tile 0..7
  const int m0 = (xcd * 8 + (s & 7)) * 128;     // token tile
  const int srow = lane >> 3;
  const int scolsw = ((lane & 7) ^ srow) * 8;
  const unsigned short* paS = wb + (size_t)(n0 + widu * 24 + srow) * 768 + scolsw;
  const unsigned short* pbS = ab + (size_t)(m0 + widu * 32 + srow) * 768 + scolsw;
  unsigned short* const ldsA = &lds[(widu * 24) * 64];
  unsigned short* const ldsB = &lds[6144 + (widu * 32) * 64];

  f32x4 acc[3][4] = {};

  for (int t = 0; t < 12; ++t) {
    const size_t c = (size_t)t * 64;
#pragma unroll
    for (int i = 0; i < 3; ++i)
      gl_lds16(paS + (size_t)i * 8 * 768 + c, ldsA + i * 8 * 64);
#pragma unroll
    for (int i = 0; i < 4; ++i)
      gl_lds16(pbS + (size_t)i * 8 * 768 + c, ldsB + i * 8 * 64);
    __syncthreads();

    bf16x8 af[3][2], bff[4][2];
#pragma unroll
    for (int m2 = 0; m2 < 3; ++m2)
#pragma unroll
      for (int kx = 0; kx < 2; ++kx)
        af[m2][kx] = *(const bf16x8*)&lds[(wr * 48 + m2 * 16 + lm) * 64 + (((kx * 4 + lq) ^ xsw) * 8)];
#pragma unroll
    for (int n2 = 0; n2 < 4; ++n2)
#pragma unroll
      for (int kx = 0; kx < 2; ++kx)
        bff[n2][kx] = *(const bf16x8*)&lds[6144 + (wc * 64 + n2 * 16 + lm) * 64 + (((kx * 4 + lq) ^ xsw) * 8)];

    __builtin_amdgcn_s_setprio(1);
#pragma unroll
    for (int kx = 0; kx < 2; ++kx)
#pragma unroll
      for (int m2 = 0; m2 < 3; ++m2)
#pragma unroll
        for (int n2 = 0; n2 < 4; ++n2)
          acc[m2][n2] = __builtin_amdgcn_mfma_f32_16x16x32_bf16(af[m2][kx], bff[n2][kx], acc[m2][n2], 0, 0, 0);
    __builtin_amdgcn_s_setprio(0);

    __syncthreads();
  }

  // acc rows = feat (n), cols = tok (m)
#pragma unroll
  for (int mi = 0; mi < 3; ++mi) {
    int gn0 = n0 + wr * 48 + mi * 16 + lq * 4;
    f32x4 bias4 = *(const f32x4*)&pb[gn0];
#pragma unroll
    for (int ni = 0; ni < 4; ++ni) {
      int gm = m0 + wc * 64 + ni * 16 + lm;
      f32x4 o;
      o[0] = acc[mi][ni][0] + bias4[0];
      o[1] = acc[mi][ni][1] + bias4[1];
      o[2] = acc[mi][ni][2] + bias4[2];
      o[3] = acc[mi][ni][3] + bias4[3];
      *(f32x4*)&out[(size_t)gm * 768 + gn0] = o;
    }
  }
}

// ---------------------------------------------------------------------------
// ws layout (bf16 elts): xb 6291456 | wqkv 1769472 | wproj 589824 |
//   q 6291456 | k 6291456 | v^T 6291456 | ao 6291456   (~67.6 MB)
// ---------------------------------------------------------------------------
extern "C" void kernel_launch(void* const* d_in, const int* in_sizes, int n_in,
                              void* d_out, int out_size, void* d_ws, size_t ws_size,
                              hipStream_t stream) {
  const float* x      = (const float*)d_in[0];
  const int*   mask   = (const int*)d_in[1];
  const float* qkv_w  = (const float*)d_in[2];
  const float* q_bias = (const float*)d_in[3];
  const float* v_bias = (const float*)d_in[4];
  const float* proj_w = (const float*)d_in[5];
  const float* proj_b = (const float*)d_in[6];
  float* out = (float*)d_out;
  unsigned short* p = (unsigned short*)d_ws;
  unsigned short* xb     = p;              p += 6291456;
  unsigned short* wqkvb  = p;              p += 1769472;
  unsigned short* wprojb = p;              p += 589824;
  unsigned short* qo     = p;              p += 6291456;
  unsigned short* ko     = p;              p += 6291456;
  unsigned short* vto    = p;              p += 6291456;
  unsigned short* ao     = p;

  cvt3_kernel<<<8448, 256, 0, stream>>>(x, xb, qkv_w, wqkvb, proj_w, wprojb);
  qkv_gemm<<<768, 256, 0, stream>>>(xb, wqkvb, q_bias, v_bias, qo, ko, vto);
  attn_mfma<<<768, 256, 0, stream>>>(qo, ko, vto, mask, ao);
  proj_gemm<<<512, 256, 0, stream>>>(ao, wprojb, proj_b, out);
}